// Round 1
// baseline (735.389 us; speedup 1.0000x reference)
//
#include <hip/hip_runtime.h>
#include <hip/hip_bf16.h>

typedef __attribute__((ext_vector_type(8))) short bf16x8;
typedef __attribute__((ext_vector_type(4))) float f32x4;
typedef unsigned short u16;

#define MFMA16(a, b, c) __builtin_amdgcn_mfma_f32_16x16x32_bf16((a), (b), (c), 0, 0, 0)

__device__ __forceinline__ u16 f2b(float f) {
  union { float f; unsigned u; } x; x.f = f;
  return (u16)((x.u + 0x7FFFu + ((x.u >> 16) & 1u)) >> 16);  // RNE
}

// ---------------- x fp32 -> bf16 ----------------
__global__ __launch_bounds__(256) void k_cvt(const float* __restrict__ in,
                                             u16* __restrict__ out, int n4) {
  int i = blockIdx.x * 256 + threadIdx.x;
  if (i >= n4) return;
  float4 v = ((const float4*)in)[i];
  u16 a = f2b(v.x), b = f2b(v.y), c = f2b(v.z), d = f2b(v.w);
  unsigned lo = (unsigned)a | ((unsigned)b << 16);
  unsigned hi = (unsigned)c | ((unsigned)d << 16);
  ((uint2*)out)[i] = make_uint2(lo, hi);
}

// ---------------- transpose+convert: out[C][R] = bf16(in[R][C]) ----------------
__global__ __launch_bounds__(256) void k_packT(const float* __restrict__ in,
                                               u16* __restrict__ out, int R, int C) {
  __shared__ float t[32][33];
  int r0 = blockIdx.x * 32, c0 = blockIdx.y * 32;
  int cx = threadIdx.x & 31, ry = threadIdx.x >> 5;
#pragma unroll
  for (int k = 0; k < 4; k++)
    t[ry + k * 8][cx] = in[(size_t)(r0 + ry + k * 8) * C + c0 + cx];
  __syncthreads();
#pragma unroll
  for (int k = 0; k < 4; k++)
    out[(size_t)(c0 + ry + k * 8) * R + r0 + cx] = f2b(t[cx][ry + k * 8]);
}

// ---------------- q,k projection: [16384][64] each, q pre-scaled by 1/8 ----------------
__global__ __launch_bounds__(256) void k_gemm_qk(const u16* __restrict__ xb,
                                                 const u16* __restrict__ wqt,
                                                 const u16* __restrict__ wkt,
                                                 u16* __restrict__ q, u16* __restrict__ kk) {
  int row0 = blockIdx.x * 64;
  int tid = threadIdx.x, w = tid >> 6, l = tid & 63, l15 = l & 15, lg = l >> 4;
  const u16* wt = (w < 2) ? wqt : wkt;
  int nbase = (w & 1) * 32;
  f32x4 acc[4][2];
#pragma unroll
  for (int mt = 0; mt < 4; mt++)
#pragma unroll
    for (int nt = 0; nt < 2; nt++) acc[mt][nt] = (f32x4){0.f, 0.f, 0.f, 0.f};

  for (int k0 = 0; k0 < 1024; k0 += 32) {
    bf16x8 bfr[2], afr[4];
#pragma unroll
    for (int nt = 0; nt < 2; nt++)
      bfr[nt] = *(const bf16x8*)&wt[(size_t)(nbase + nt * 16 + l15) * 1024 + k0 + lg * 8];
#pragma unroll
    for (int mt = 0; mt < 4; mt++)
      afr[mt] = *(const bf16x8*)&xb[(size_t)(row0 + mt * 16 + l15) * 1024 + k0 + lg * 8];
#pragma unroll
    for (int mt = 0; mt < 4; mt++)
#pragma unroll
      for (int nt = 0; nt < 2; nt++) acc[mt][nt] = MFMA16(afr[mt], bfr[nt], acc[mt][nt]);
  }
  float scale = (w < 2) ? 0.125f : 1.0f;  // fold head_size^-0.5 into q
  u16* dst = (w < 2) ? q : kk;
#pragma unroll
  for (int mt = 0; mt < 4; mt++)
#pragma unroll
    for (int nt = 0; nt < 2; nt++)
#pragma unroll
      for (int j = 0; j < 4; j++)
        dst[(size_t)(row0 + mt * 16 + lg * 4 + j) * 64 + nbase + nt * 16 + l15] =
            f2b(acc[mt][nt][j] * scale);
}

// ---------------- v projection, transposed: vT[b][d][s] = sum_k Wv[k][d] x[b][s][k] ----------------
__global__ __launch_bounds__(256) void k_gemm_v(const u16* __restrict__ xb,
                                                const u16* __restrict__ wvt,
                                                u16* __restrict__ vT) {
  int b = blockIdx.z;
  int m0 = blockIdx.y * 128;  // d_out
  int n0 = blockIdx.x * 128;  // s
  int tid = threadIdx.x, w = tid >> 6, l = tid & 63, l15 = l & 15, lg = l >> 4;
  int nb = n0 + w * 32;
  const u16* xrow = xb + (size_t)(b * 4096 + nb) * 1024;
  f32x4 acc[8][2];
#pragma unroll
  for (int mt = 0; mt < 8; mt++)
#pragma unroll
    for (int nt = 0; nt < 2; nt++) acc[mt][nt] = (f32x4){0.f, 0.f, 0.f, 0.f};

  for (int k0 = 0; k0 < 1024; k0 += 32) {
    bf16x8 bfr[2], afr[8];
#pragma unroll
    for (int nt = 0; nt < 2; nt++)
      bfr[nt] = *(const bf16x8*)&xrow[(size_t)(nt * 16 + l15) * 1024 + k0 + lg * 8];
#pragma unroll
    for (int mt = 0; mt < 8; mt++)
      afr[mt] = *(const bf16x8*)&wvt[(size_t)(m0 + mt * 16 + l15) * 1024 + k0 + lg * 8];
#pragma unroll
    for (int mt = 0; mt < 8; mt++)
#pragma unroll
      for (int nt = 0; nt < 2; nt++) acc[mt][nt] = MFMA16(afr[mt], bfr[nt], acc[mt][nt]);
  }
#pragma unroll
  for (int mt = 0; mt < 8; mt++)
#pragma unroll
    for (int nt = 0; nt < 2; nt++)
#pragma unroll
      for (int j = 0; j < 4; j++)
        vT[((size_t)b * 1024 + m0 + mt * 16 + lg * 4 + j) * 4096 + nb + nt * 16 + l15] =
            f2b(acc[mt][nt][j]);
}

// ---------------- flash attention: 8 waves, BM=64 q, BN=64 kv, Dchunk=256 ----------------
__global__ __launch_bounds__(512) void k_attn(const u16* __restrict__ qw,
                                              const u16* __restrict__ kw,
                                              const u16* __restrict__ vT,
                                              float* __restrict__ out) {
  int bx = blockIdx.x;
  int qtile = bx & 63, rest = bx >> 6;
  int chunk = rest & 3, b = rest >> 2;
  int q0 = qtile * 64, d0 = chunk * 256;
  int tid = threadIdx.x, w = tid >> 6, l = tid & 63, l15 = l & 15, lg = l >> 4;
  int qt = w >> 1, st2 = w & 1;

  __shared__ float m_s[64], l_s[64], sc_s[64], pm[2][64], lp[2][64];
  __shared__ __align__(16) u16 P[64 * 64];  // swizzled bf16 probs

  if (tid < 64) { m_s[tid] = -1e30f; l_s[tid] = 0.f; }

  size_t tokb = (size_t)b * 4096;
  bf16x8 qf[2];
#pragma unroll
  for (int ks = 0; ks < 2; ks++)
    qf[ks] = *(const bf16x8*)&qw[(tokb + q0 + qt * 16 + l15) * 64 + ks * 32 + lg * 8];

  f32x4 acc[2][4];
#pragma unroll
  for (int mt = 0; mt < 2; mt++)
#pragma unroll
    for (int nt = 0; nt < 4; nt++) acc[mt][nt] = (f32x4){0.f, 0.f, 0.f, 0.f};

  const size_t vrow0 = (size_t)b * 1024 + d0 + w * 32;
  __syncthreads();

  int ntiles = qtile + 1;
  for (int t = 0; t < ntiles; t++) {
    int s0 = t * 64;
    bf16x8 va[2][2], kf[2][2];
#pragma unroll
    for (int mt = 0; mt < 2; mt++)  // prefetch V^T frags early: consumed only in PV
#pragma unroll
      for (int ks = 0; ks < 2; ks++)
        va[mt][ks] = *(const bf16x8*)&vT[(vrow0 + mt * 16 + l15) * 4096 + s0 + ks * 32 + lg * 8];
#pragma unroll
    for (int sti = 0; sti < 2; sti++)
#pragma unroll
      for (int ks = 0; ks < 2; ks++)
        kf[sti][ks] =
            *(const bf16x8*)&kw[(tokb + s0 + (st2 * 2 + sti) * 16 + l15) * 64 + ks * 32 + lg * 8];

    // S = (q/8) k^T : wave computes tiles (qt, st2*2+{0,1}); rows=q (lg*4+j), cols=s (l15)
    f32x4 sfr[2];
#pragma unroll
    for (int sti = 0; sti < 2; sti++) {
      sfr[sti] = (f32x4){0.f, 0.f, 0.f, 0.f};
#pragma unroll
      for (int ks = 0; ks < 2; ks++) sfr[sti] = MFMA16(qf[ks], kf[sti][ks], sfr[sti]);
    }

    if (t == ntiles - 1) {  // diagonal tile: causal mask
#pragma unroll
      for (int sti = 0; sti < 2; sti++) {
        int sg = s0 + (st2 * 2 + sti) * 16 + l15;
#pragma unroll
        for (int j = 0; j < 4; j++)
          if (sg > q0 + qt * 16 + lg * 4 + j) sfr[sti][j] = -1e30f;
      }
    }

    // wave-parallel partial row-max over this wave's 32 cols
    float pmax[4];
#pragma unroll
    for (int j = 0; j < 4; j++) pmax[j] = fmaxf(sfr[0][j], sfr[1][j]);
#pragma unroll
    for (int msk = 1; msk <= 8; msk <<= 1)
#pragma unroll
      for (int j = 0; j < 4; j++) pmax[j] = fmaxf(pmax[j], __shfl_xor(pmax[j], msk));
    if (l15 == 0) {
#pragma unroll
      for (int j = 0; j < 4; j++) pm[st2][qt * 16 + lg * 4 + j] = pmax[j];
    }
    __syncthreads();
    if (tid < 64) {
      float mo = m_s[tid];
      float mn = fmaxf(mo, fmaxf(pm[0][tid], pm[1][tid]));
      m_s[tid] = mn;
      sc_s[tid] = __expf(mo - mn);
    }
    __syncthreads();

    // P = exp(S - m_new) -> swizzled LDS bf16; partial row-sums
    float psum[4] = {0.f, 0.f, 0.f, 0.f};
#pragma unroll
    for (int j = 0; j < 4; j++) {
      int row = qt * 16 + lg * 4 + j;
      float mn = m_s[row];
#pragma unroll
      for (int sti = 0; sti < 2; sti++) {
        float p = __expf(sfr[sti][j] - mn);
        psum[j] += p;
        int col = (st2 * 2 + sti) * 16 + l15;
        int addr = (row * 128 + col * 2) ^ ((row & 7) << 4);
        *(u16*)((char*)P + addr) = f2b(p);
      }
    }
#pragma unroll
    for (int msk = 1; msk <= 8; msk <<= 1)
#pragma unroll
      for (int j = 0; j < 4; j++) psum[j] += __shfl_xor(psum[j], msk);
    if (l15 == 0) {
#pragma unroll
      for (int j = 0; j < 4; j++) lp[st2][qt * 16 + lg * 4 + j] = psum[j];
    }
    // O rescale (acc cols = q = nt*16 + l15)
    float scl[4];
#pragma unroll
    for (int nt = 0; nt < 4; nt++) scl[nt] = sc_s[nt * 16 + l15];
#pragma unroll
    for (int mt = 0; mt < 2; mt++)
#pragma unroll
      for (int nt = 0; nt < 4; nt++) acc[mt][nt] *= scl[nt];
    __syncthreads();
    if (tid < 64) l_s[tid] = l_s[tid] * sc_s[tid] + lp[0][tid] + lp[1][tid];

    // O^T += V^T P^T : A=va (m=d), B=P frags (k=s contiguous, n=q)
#pragma unroll
    for (int ks = 0; ks < 2; ks++) {
#pragma unroll
      for (int nt = 0; nt < 4; nt++) {
        int row = nt * 16 + l15;
        int addr = (row * 128 + (ks * 32 + lg * 8) * 2) ^ ((row & 7) << 4);
        bf16x8 pf = *(const bf16x8*)((const char*)P + addr);
#pragma unroll
        for (int mt = 0; mt < 2; mt++) acc[mt][nt] = MFMA16(va[mt][ks], pf, acc[mt][nt]);
      }
    }
  }
  __syncthreads();
  float linv[4];
#pragma unroll
  for (int nt = 0; nt < 4; nt++) linv[nt] = 1.f / l_s[nt * 16 + l15];
#pragma unroll
  for (int mt = 0; mt < 2; mt++)
#pragma unroll
    for (int nt = 0; nt < 4; nt++) {
      f32x4 v = acc[mt][nt] * linv[nt];
      size_t o = (tokb + q0 + nt * 16 + l15) * 1024 + d0 + w * 32 + mt * 16 + lg * 4;
      *(f32x4*)&out[o] = v;  // rows j are consecutive d -> coalesced 16B stores
    }
}

// ---------------- launch ----------------
extern "C" void kernel_launch(void* const* d_in, const int* in_sizes, int n_in,
                              void* d_out, int out_size, void* d_ws, size_t ws_size,
                              hipStream_t stream) {
  const float* x  = (const float*)d_in[0];
  const float* Wq = (const float*)d_in[1];
  const float* Wk = (const float*)d_in[2];
  const float* Wv = (const float*)d_in[3];
  float* out = (float*)d_out;
  char* ws = (char*)d_ws;
  // ws layout (bytes): total ~73.7 MB
  u16* xb  = (u16*)(ws);              // 16384x1024 bf16   33,554,432
  u16* qw  = (u16*)(ws + 33554432);   // 16384x64          2,097,152
  u16* kw  = (u16*)(ws + 35651584);   // 16384x64          2,097,152
  u16* vT  = (u16*)(ws + 37748736);   // 4x1024x4096       33,554,432
  u16* wqt = (u16*)(ws + 71303168);   // 64x1024           131,072
  u16* wkt = (u16*)(ws + 71434240);   // 64x1024           131,072
  u16* wvt = (u16*)(ws + 71565312);   // 1024x1024         2,097,152

  k_cvt<<<16384, 256, 0, stream>>>(x, xb, 4194304);
  k_packT<<<dim3(32, 2), 256, 0, stream>>>(Wq, wqt, 1024, 64);
  k_packT<<<dim3(32, 2), 256, 0, stream>>>(Wk, wkt, 1024, 64);
  k_packT<<<dim3(32, 32), 256, 0, stream>>>(Wv, wvt, 1024, 1024);
  k_gemm_qk<<<256, 256, 0, stream>>>(xb, wqt, wkt, qw, kw);
  k_gemm_v<<<dim3(32, 8, 4), 256, 0, stream>>>(xb, wvt, vT);
  k_attn<<<1024, 512, 0, stream>>>(qw, kw, vT, out);
}